// Round 4
// baseline (350.825 us; speedup 1.0000x reference)
//
#include <hip/hip_runtime.h>

#define T 32
#define C 2048
#define NTOT 600
#define NCLASS 20
#define NSUP 5
#define PER 30
#define NQPC 25
#define NQ 500
#define NQROWS (NQ * T)      // 16000
#define NPROWS (NCLASS * T)  // 640
#define GAMMA 0.1f
#define INVG 10.0f
#define BIG 1e10f
#define NMM (NQ * NCLASS + NQ + NCLASS)  // 10520
#define NBLKA (NQROWS / 32)  // 500
#define NBLKB (NPROWS / 32)  // 20
#define GEMM_BLKS 625
#define SYRK_BLKS 130

typedef short bf16x8 __attribute__((ext_vector_type(8)));
typedef float f32x4 __attribute__((ext_vector_type(4)));

__device__ __forceinline__ void gload16(const void* g, void* l) {
    __builtin_amdgcn_global_load_lds((const __attribute__((address_space(1))) void*)g,
                                     (__attribute__((address_space(3))) void*)l, 16, 0, 0);
}

__device__ __forceinline__ unsigned bf16_rne(float f) {
    unsigned u = __float_as_uint(f);
    return (u + 0x7fffu + ((u >> 16) & 1u)) >> 16;
}

// ---------------- parallel stable counting sort (1 block) ----------------
__global__ __launch_bounds__(640) void sort_kernel(const int* __restrict__ target,
                                                   int* __restrict__ order,
                                                   int* __restrict__ qsrc) {
    __shared__ int tgt[NTOT];
    __shared__ int offs[NCLASS];
    __shared__ int ordl[NTOT];
    int tid = threadIdx.x;
    if (tid < NTOT) tgt[tid] = target[tid];
    __syncthreads();
    if (tid < NCLASS) {
        int o = 0;
        for (int i = 0; i < NTOT; i++) o += (tgt[i] < tid) ? 1 : 0;
        offs[tid] = o;
    }
    __syncthreads();
    if (tid < NTOT) {
        int c = tgt[tid];
        int rank = 0;
        for (int k = 0; k < NTOT; k++) rank += (k < tid && tgt[k] == c) ? 1 : 0;
        ordl[offs[c] + rank] = tid;
    }
    __syncthreads();
    if (tid < NTOT) order[tid] = ordl[tid];
    if (tid < NQ) qsrc[tid] = ordl[(tid / NQPC) * PER + NSUP + (tid % NQPC)];
}

// ---------------- unified staging: gather/mean + hi/lo split + norms ----------------
// 32 rows per block, LDS transpose -> 512B-contiguous global writes.
// dst layout contract: dst[chunk*nrows + row] : bf16x8 covering cols [chunk*8, chunk*8+8)
__global__ __launch_bounds__(256) void stage_kernel(const float* __restrict__ inp,
                                                    const int* __restrict__ qsrc,
                                                    const int* __restrict__ order,
                                                    bf16x8* __restrict__ Ah,
                                                    bf16x8* __restrict__ Al,
                                                    bf16x8* __restrict__ Bh,
                                                    bf16x8* __restrict__ Bl,
                                                    float* __restrict__ x2,
                                                    float* __restrict__ y2) {
    __shared__ bf16x8 lh[32][32];
    __shared__ bf16x8 ll[32][32];
    int tid = threadIdx.x;
    int r = tid >> 3, p = tid & 7;
    int blk = blockIdx.x;
    bool isA = blk < NBLKA;
    int row0 = isA ? blk * 32 : (blk - NBLKA) * 32;
    int rowg = row0 + r;
    bf16x8* dhi;
    bf16x8* dlo;
    int nrows;
    float* nrm;
    const float *s0, *s1, *s2, *s3, *s4;
    if (isA) {
        dhi = Ah; dlo = Al; nrows = NQROWS; nrm = x2;
        s0 = inp + (size_t)qsrc[rowg >> 5] * (T * C) + (size_t)(rowg & 31) * C;
        s1 = s2 = s3 = s4 = s0;
    } else {
        dhi = Bh; dlo = Bl; nrows = NPROWS; nrm = y2;
        int cls = rowg >> 5, trow = rowg & 31;
        s0 = inp + (size_t)order[cls * PER + 0] * (T * C) + (size_t)trow * C;
        s1 = inp + (size_t)order[cls * PER + 1] * (T * C) + (size_t)trow * C;
        s2 = inp + (size_t)order[cls * PER + 2] * (T * C) + (size_t)trow * C;
        s3 = inp + (size_t)order[cls * PER + 3] * (T * C) + (size_t)trow * C;
        s4 = inp + (size_t)order[cls * PER + 4] * (T * C) + (size_t)trow * C;
    }
    float sumsq = 0.f;
#pragma unroll 1
    for (int s = 0; s < 8; s++) {
        int colb = s * 256 + p * 32;
        float vals[32];
        if (isA) {
#pragma unroll
            for (int i = 0; i < 8; i++) {
                float4 v = *(const float4*)(s0 + colb + i * 4);
                vals[i * 4 + 0] = v.x; vals[i * 4 + 1] = v.y;
                vals[i * 4 + 2] = v.z; vals[i * 4 + 3] = v.w;
            }
        } else {
#pragma unroll
            for (int i = 0; i < 8; i++) {
                float4 a = *(const float4*)(s0 + colb + i * 4);
                float4 b = *(const float4*)(s1 + colb + i * 4);
                float4 c = *(const float4*)(s2 + colb + i * 4);
                float4 d = *(const float4*)(s3 + colb + i * 4);
                float4 e = *(const float4*)(s4 + colb + i * 4);
                vals[i * 4 + 0] = (a.x + b.x + c.x + d.x + e.x) * 0.2f;
                vals[i * 4 + 1] = (a.y + b.y + c.y + d.y + e.y) * 0.2f;
                vals[i * 4 + 2] = (a.z + b.z + c.z + d.z + e.z) * 0.2f;
                vals[i * 4 + 3] = (a.w + b.w + c.w + d.w + e.w) * 0.2f;
            }
        }
        bf16x8 hv[4], lv[4];
#pragma unroll
        for (int e = 0; e < 32; e++) {
            float f = vals[e];
            sumsq += f * f;
            unsigned hb = bf16_rne(f);
            float lof = f - __uint_as_float(hb << 16);
            hv[e >> 3][e & 7] = (short)hb;
            lv[e >> 3][e & 7] = (short)bf16_rne(lof);
        }
        __syncthreads();  // previous segment's out-writes done before LDS overwrite
#pragma unroll
        for (int i = 0; i < 4; i++) {
            lh[p * 4 + i][r] = hv[i];
            ll[p * 4 + i][r] = lv[i];
        }
        __syncthreads();
#pragma unroll
        for (int w = 0; w < 4; w++) {
            int idx = w * 256 + tid;
            int cc = idx >> 5, r2 = idx & 31;
            size_t o = (size_t)(s * 32 + cc) * nrows + row0 + r2;
            dhi[o] = lh[cc][r2];
            dlo[o] = ll[cc][r2];
        }
    }
#pragma unroll
    for (int d = 1; d < 8; d <<= 1) sumsq += __shfl_xor(sumsq, d);
    if (p == 0) nrm[rowg] = sumsq;
}

// ---------------- merged: split-bf16 MFMA GEMM (blocks 0..624) + SYRK (625..754) ----
__global__ __launch_bounds__(256) void gemm_syrk_kernel(const bf16x8* __restrict__ Ah,
                                                        const bf16x8* __restrict__ Al,
                                                        const bf16x8* __restrict__ Bh,
                                                        const bf16x8* __restrict__ Bl,
                                                        float* __restrict__ xy,
                                                        float* __restrict__ gxx,
                                                        float* __restrict__ gyy) {
    __shared__ bf16x8 sAh[512], sAl[512], sBh[512], sBl[512];  // 32 KB
    int tid = threadIdx.x, lane = tid & 63, wid = tid >> 6;
    int o = blockIdx.x;
    if (o >= GEMM_BLKS) {
        // ---- SYRK path: one wave per 32x32 Gram matrix ----
        int ww = (o - GEMM_BLKS) * 4 + wid;
        const bf16x8* hi;
        const bf16x8* lo;
        int nrows, row0;
        float* outp;
        if (ww < NQ) {
            hi = Ah; lo = Al; nrows = NQROWS; row0 = ww * 32;
            outp = gxx + (size_t)ww * (T * T);
        } else {
            hi = Bh; lo = Bl; nrows = NPROWS; row0 = (ww - NQ) * 32;
            outp = gyy + (size_t)(ww - NQ) * (T * T);
        }
        int r = lane & 15, g = lane >> 4;
        f32x4 acc[2][2];
        f32x4 zero = {0.f, 0.f, 0.f, 0.f};
        acc[0][0] = zero; acc[0][1] = zero; acc[1][0] = zero; acc[1][1] = zero;
        for (int t = 0; t < C / 32; t++) {
            size_t base = (size_t)(t * 4 + g) * nrows + row0 + r;
            bf16x8 h0 = hi[base], h1 = hi[base + 16];
            bf16x8 l0 = lo[base], l1 = lo[base + 16];
            acc[0][0] = __builtin_amdgcn_mfma_f32_16x16x32_bf16(h0, h0, acc[0][0], 0, 0, 0);
            acc[0][0] = __builtin_amdgcn_mfma_f32_16x16x32_bf16(h0, l0, acc[0][0], 0, 0, 0);
            acc[0][0] = __builtin_amdgcn_mfma_f32_16x16x32_bf16(l0, h0, acc[0][0], 0, 0, 0);
            acc[0][1] = __builtin_amdgcn_mfma_f32_16x16x32_bf16(h0, h1, acc[0][1], 0, 0, 0);
            acc[0][1] = __builtin_amdgcn_mfma_f32_16x16x32_bf16(h0, l1, acc[0][1], 0, 0, 0);
            acc[0][1] = __builtin_amdgcn_mfma_f32_16x16x32_bf16(l0, h1, acc[0][1], 0, 0, 0);
            acc[1][0] = __builtin_amdgcn_mfma_f32_16x16x32_bf16(h1, h0, acc[1][0], 0, 0, 0);
            acc[1][0] = __builtin_amdgcn_mfma_f32_16x16x32_bf16(h1, l0, acc[1][0], 0, 0, 0);
            acc[1][0] = __builtin_amdgcn_mfma_f32_16x16x32_bf16(l1, h0, acc[1][0], 0, 0, 0);
            acc[1][1] = __builtin_amdgcn_mfma_f32_16x16x32_bf16(h1, h1, acc[1][1], 0, 0, 0);
            acc[1][1] = __builtin_amdgcn_mfma_f32_16x16x32_bf16(h1, l1, acc[1][1], 0, 0, 0);
            acc[1][1] = __builtin_amdgcn_mfma_f32_16x16x32_bf16(l1, h1, acc[1][1], 0, 0, 0);
        }
#pragma unroll
        for (int mi = 0; mi < 2; mi++)
#pragma unroll
            for (int ni = 0; ni < 2; ni++)
#pragma unroll
                for (int j = 0; j < 4; j++)
                    outp[(mi * 16 + g * 4 + j) * T + ni * 16 + r] = acc[mi][ni][j];
        return;
    }
    // ---- GEMM path ----
    // bijective XCD swizzle over 625 = 8*78+1
    int xcd = o & 7, slot = o >> 3;
    int v = (xcd < 1 ? xcd * 79 : 79 + (xcd - 1) * 78) + slot;
    int bm = v / 5, bn = v % 5;
    int wr = wid >> 1, wc = wid & 1;
    int m0 = bm * 128, n0 = bn * 128;
    int i0 = tid, i1 = tid + 256;
    const bf16x8* gAh0 = Ah + (size_t)(i0 >> 7) * NQROWS + m0 + (i0 & 127);
    const bf16x8* gAh1 = Ah + (size_t)(i1 >> 7) * NQROWS + m0 + (i1 & 127);
    const bf16x8* gAl0 = Al + (size_t)(i0 >> 7) * NQROWS + m0 + (i0 & 127);
    const bf16x8* gAl1 = Al + (size_t)(i1 >> 7) * NQROWS + m0 + (i1 & 127);
    const bf16x8* gBh0 = Bh + (size_t)(i0 >> 7) * NPROWS + n0 + (i0 & 127);
    const bf16x8* gBh1 = Bh + (size_t)(i1 >> 7) * NPROWS + n0 + (i1 & 127);
    const bf16x8* gBl0 = Bl + (size_t)(i0 >> 7) * NPROWS + n0 + (i0 & 127);
    const bf16x8* gBl1 = Bl + (size_t)(i1 >> 7) * NPROWS + n0 + (i1 & 127);
    f32x4 acc[4][4];
    f32x4 zero = {0.f, 0.f, 0.f, 0.f};
#pragma unroll
    for (int mi = 0; mi < 4; mi++)
#pragma unroll
        for (int ni = 0; ni < 4; ni++) acc[mi][ni] = zero;
    int g = lane >> 4, r = lane & 15;
    int aoff = g * 128 + wr * 64 + r;
    int boff = g * 128 + wc * 64 + r;
    for (int t = 0; t < C / 32; t++) {
        gload16(gAh0, &sAh[i0]); gload16(gAh1, &sAh[i1]);
        gload16(gAl0, &sAl[i0]); gload16(gAl1, &sAl[i1]);
        gload16(gBh0, &sBh[i0]); gload16(gBh1, &sBh[i1]);
        gload16(gBl0, &sBl[i0]); gload16(gBl1, &sBl[i1]);
        gAh0 += 4 * NQROWS; gAh1 += 4 * NQROWS; gAl0 += 4 * NQROWS; gAl1 += 4 * NQROWS;
        gBh0 += 4 * NPROWS; gBh1 += 4 * NPROWS; gBl0 += 4 * NPROWS; gBl1 += 4 * NPROWS;
        __syncthreads();
        bf16x8 ah[4], al[4], bh[4], bl[4];
#pragma unroll
        for (int i = 0; i < 4; i++) {
            ah[i] = sAh[aoff + i * 16];
            al[i] = sAl[aoff + i * 16];
            bh[i] = sBh[boff + i * 16];
            bl[i] = sBl[boff + i * 16];
        }
#pragma unroll
        for (int mi = 0; mi < 4; mi++)
#pragma unroll
            for (int ni = 0; ni < 4; ni++) {
                acc[mi][ni] = __builtin_amdgcn_mfma_f32_16x16x32_bf16(ah[mi], bh[ni], acc[mi][ni], 0, 0, 0);
                acc[mi][ni] = __builtin_amdgcn_mfma_f32_16x16x32_bf16(ah[mi], bl[ni], acc[mi][ni], 0, 0, 0);
                acc[mi][ni] = __builtin_amdgcn_mfma_f32_16x16x32_bf16(al[mi], bh[ni], acc[mi][ni], 0, 0, 0);
            }
        __syncthreads();
    }
    int orow = m0 + wr * 64 + (lane >> 4) * 4;
    int ocol = n0 + wc * 64 + (lane & 15);
#pragma unroll
    for (int mi = 0; mi < 4; mi++)
#pragma unroll
        for (int ni = 0; ni < 4; ni++)
#pragma unroll
            for (int j = 0; j < 4; j++)
                xy[(size_t)(orow + mi * 16 + j) * NPROWS + ocol + ni * 16] = acc[mi][ni][j];
}

// ---------------- merged soft-DTW DP: one thread per 32x32 cost matrix ----------------
__global__ void softdtw_all_kernel(const float* __restrict__ xy, const float* __restrict__ gxx,
                                   const float* __restrict__ gyy, const float* __restrict__ x2,
                                   const float* __restrict__ y2, float* __restrict__ dxy,
                                   float* __restrict__ dxx, float* __restrict__ dyy) {
    int mm = blockIdx.x * 64 + threadIdx.x;
    if (mm >= NMM) return;
    const float* rterm;
    const float* cterm;
    const float* cptr;
    int cstride;
    float* outp;
    if (mm < NQ * NCLASS) {
        int q = mm / NCLASS, m = mm % NCLASS;
        rterm = x2 + q * T;
        cterm = y2 + m * T;
        cptr = xy + (size_t)(q * T) * NPROWS + m * T;
        cstride = NPROWS;
        outp = dxy + mm;
    } else if (mm < NQ * NCLASS + NQ) {
        int i = mm - NQ * NCLASS;
        rterm = x2 + i * T;
        cterm = rterm;
        cptr = gxx + (size_t)i * (T * T);
        cstride = T;
        outp = dxx + i;
    } else {
        int i = mm - NQ * NCLASS - NQ;
        rterm = y2 + i * T;
        cterm = rterm;
        cptr = gyy + (size_t)i * (T * T);
        cstride = T;
        outp = dyy + i;
    }
    float cj[T];
#pragma unroll
    for (int j = 0; j < T; j++) cj[j] = cterm[j];
    float Rp[T + 1];
    Rp[0] = 0.f;
#pragma unroll
    for (int j = 1; j <= T; j++) Rp[j] = BIG;
    for (int i = 0; i < T; i++) {
        float diag = Rp[0];
        Rp[0] = BIG;
        float left = BIG;
        float ai = rterm[i];
        const float4* crow4 = (const float4*)(cptr + (size_t)i * cstride);
        float cr[T];
#pragma unroll
        for (int jj = 0; jj < 8; jj++) {
            float4 v = crow4[jj];
            cr[jj * 4 + 0] = v.x; cr[jj * 4 + 1] = v.y;
            cr[jj * 4 + 2] = v.z; cr[jj * 4 + 3] = v.w;
        }
#pragma unroll
        for (int j = 0; j < T; j++) {
            float up = Rp[j + 1];
            float d = ai + cj[j] - 2.0f * cr[j];
            float mn = fminf(diag, fminf(up, left));
            float ssum = __expf((mn - diag) * INVG) + __expf((mn - up) * INVG) +
                         __expf((mn - left) * INVG);
            float rr = d + mn - GAMMA * __logf(ssum);
            diag = up;
            Rp[j + 1] = rr;
            left = rr;
        }
    }
    *outp = Rp[T];
}

// ---------------- finalize: dist, log-softmax, loss, acc ----------------
__global__ __launch_bounds__(512) void finalize_kernel(const float* __restrict__ dxy,
                                                       const float* __restrict__ dxx,
                                                       const float* __restrict__ dyy,
                                                       float* __restrict__ out) {
    __shared__ float sl[512];
    __shared__ float sa[512];
    int q = threadIdx.x;
    float bl = 0.f, fl = 0.f;
    if (q < NQ) {
        float dxxq = dxx[q];
        int cq = q / NQPC;
        float dd[NCLASS];
#pragma unroll
        for (int m = 0; m < NCLASS; m++)
            dd[m] = dxy[q * NCLASS + m] - 0.5f * (dxxq + dyy[m]);
        float best = dd[0];
        int bi = 0;
#pragma unroll
        for (int m = 1; m < NCLASS; m++) {
            if (dd[m] < best) { best = dd[m]; bi = m; }
        }
        float s = 0.f;
        float dcq = dd[0];
#pragma unroll
        for (int m = 0; m < NCLASS; m++) {
            s += __expf(best - dd[m]);
            if (m == cq) dcq = dd[m];
        }
        float lse = __logf(s) - best;
        bl = dcq + lse;
        out[2 + q] = bl;
        fl = (bi == cq) ? 1.f : 0.f;
    }
    sl[threadIdx.x] = bl;
    sa[threadIdx.x] = fl;
    __syncthreads();
    for (int off = 256; off; off >>= 1) {
        if (threadIdx.x < off) {
            sl[threadIdx.x] += sl[threadIdx.x + off];
            sa[threadIdx.x] += sa[threadIdx.x + off];
        }
        __syncthreads();
    }
    if (threadIdx.x == 0) {
        out[0] = sl[0] / (float)NQ;
        out[1] = sa[0] / (float)NQ;
    }
}

extern "C" void kernel_launch(void* const* d_in, const int* in_sizes, int n_in,
                              void* d_out, int out_size, void* d_ws, size_t ws_size,
                              hipStream_t stream) {
    const float* inp = (const float*)d_in[0];
    const int* target = (const int*)d_in[1];
    float* out = (float*)d_out;
    char* ws = (char*)d_ws;

    size_t off = 0;
    auto carve = [&](size_t bytes) {
        void* p = ws + off;
        off = (off + bytes + 255) & ~(size_t)255;
        return p;
    };
    int* order = (int*)carve(NTOT * sizeof(int));
    int* qsrc = (int*)carve(NQ * sizeof(int));
    float* x2 = (float*)carve((size_t)NQROWS * sizeof(float));
    float* y2 = (float*)carve((size_t)NPROWS * sizeof(float));
    float* xy = (float*)carve((size_t)NQROWS * NPROWS * sizeof(float));  // 41 MB
    float* gxx = (float*)carve((size_t)NQ * T * T * sizeof(float));
    float* gyy = (float*)carve((size_t)NCLASS * T * T * sizeof(float));
    float* dxy = (float*)carve((size_t)NQ * NCLASS * sizeof(float));
    float* dxx = (float*)carve((size_t)NQ * sizeof(float));
    float* dyy = (float*)carve((size_t)NCLASS * sizeof(float));
    bf16x8* Ah = (bf16x8*)carve((size_t)(C / 8) * NQROWS * 16);  // 65.5 MB
    bf16x8* Al = (bf16x8*)carve((size_t)(C / 8) * NQROWS * 16);
    bf16x8* Bh = (bf16x8*)carve((size_t)(C / 8) * NPROWS * 16);  // 2.6 MB
    bf16x8* Bl = (bf16x8*)carve((size_t)(C / 8) * NPROWS * 16);
    (void)ws_size;

    sort_kernel<<<1, 640, 0, stream>>>(target, order, qsrc);
    stage_kernel<<<NBLKA + NBLKB, 256, 0, stream>>>(inp, qsrc, order, Ah, Al, Bh, Bl, x2, y2);
    gemm_syrk_kernel<<<GEMM_BLKS + SYRK_BLKS, 256, 0, stream>>>(Ah, Al, Bh, Bl, xy, gxx, gyy);
    softdtw_all_kernel<<<(NMM + 63) / 64, 64, 0, stream>>>(xy, gxx, gyy, x2, y2, dxy, dxx, dyy);
    finalize_kernel<<<1, 512, 0, stream>>>(dxy, dxx, dyy, out);
}